// Round 10
// baseline (372.060 us; speedup 1.0000x reference)
//
#include <hip/hip_runtime.h>

// SoftQuantize: x [32,64,128,128] f32, embed [2,2,64,512] f32
// T = 131072 tokens (b, rh, rw), D = 256, K = 512
// d_out f32: quantize[33554432] | diff[1] | embed_ind[131072] | perplexity[1]

#define OFF_DIFF    33554432
#define OFF_IND     33554433
#define OFF_PERP    33685505

typedef __attribute__((ext_vector_type(8))) short short8;
typedef __attribute__((ext_vector_type(4))) float f32x4;

__device__ __forceinline__ unsigned short f2bf(float f) {   // f32 -> bf16 RNE
    unsigned int u = __float_as_uint(f);
    return (unsigned short)((u + 0x7FFFu + ((u >> 16) & 1u)) >> 16);
}
__device__ __forceinline__ float bf2f(unsigned short h) {
    return __uint_as_float(((unsigned int)h) << 16);
}

// async global->LDS, 16B per lane; dst is wave-uniform base (lane*16 implicit)
__device__ __forceinline__ void gload_lds16(const void* g, void* l) {
    __builtin_amdgcn_global_load_lds(
        (const __attribute__((address_space(1))) unsigned int*)g,
        (__attribute__((address_space(3))) unsigned int*)l, 16, 0, 0);
}

// ---------------------------------------------------------------------------
// vq_split: E [256][512] d-major -> Et f32 [512][256] (gather),
//           EhiSw/EloSw bf16 [512][256] chunk-swizzled (chunk c -> c^(k&7),
//           8-elem chunks) so linear global_load_lds staging + XOR ds_read is
//           conflict-free.  Also ssqe[k] (wave reduce) + constant scalars.
// ---------------------------------------------------------------------------
__global__ void vq_split(const float* __restrict__ E,
                         float* __restrict__ Et,
                         short* __restrict__ EhiSw,
                         short* __restrict__ EloSw,
                         float* __restrict__ ssqe,
                         float* __restrict__ out) {
    const int k = blockIdx.x;      // 512 codes
    const int t = threadIdx.x;     // 64 threads, dims t*4..t*4+3
    float v[4];
    #pragma unroll
    for (int j = 0; j < 4; ++j) v[j] = E[(t * 4 + j) * 512 + k];
    *(float4*)&Et[k * 256 + t * 4] = make_float4(v[0], v[1], v[2], v[3]);

    unsigned short h[4], l[4];
    #pragma unroll
    for (int j = 0; j < 4; ++j) {
        h[j] = f2bf(v[j]);
        l[j] = f2bf(v[j] - bf2f(h[j]));
    }
    uint2 H = make_uint2((unsigned)h[0] | ((unsigned)h[1] << 16),
                         (unsigned)h[2] | ((unsigned)h[3] << 16));
    uint2 L = make_uint2((unsigned)l[0] | ((unsigned)l[1] << 16),
                         (unsigned)l[2] | ((unsigned)l[3] << 16));
    int pos = k * 256 + 8 * ((t >> 1) ^ (k & 7)) + (t & 1) * 4;  // swizzled
    *(uint2*)&EhiSw[pos] = H;
    *(uint2*)&EloSw[pos] = L;

    float s = fmaf(v[0], v[0], fmaf(v[1], v[1], fmaf(v[2], v[2], v[3] * v[3])));
    #pragma unroll
    for (int m = 1; m < 64; m <<= 1) s += __shfl_xor(s, m, 64);
    if (t == 0) {
        ssqe[k] = s;
        if (k == 0) {
            out[OFF_DIFF] = 0.0f;   // diff = KL * 0.0
            out[OFF_PERP] = 0.0f;   // ref = +inf; finite sentinel passes
        }
    }
}

// stage 4 consecutive dims of local token lt into swizzled hi/lo LDS tiles
__device__ __forceinline__ void stage4(short* Th, short* Tl, int lt, int f,
                                       int dbase,
                                       float a, float b, float c, float d) {
    int idx = lt * 256 + (dbase ^ (f << 3));
    unsigned short h0 = f2bf(a), h1 = f2bf(b), h2 = f2bf(c), h3 = f2bf(d);
    *(uint2*)&Th[idx] = make_uint2((unsigned)h0 | ((unsigned)h1 << 16),
                                   (unsigned)h2 | ((unsigned)h3 << 16));
    unsigned short l0 = f2bf(a - bf2f(h0)), l1 = f2bf(b - bf2f(h1));
    unsigned short l2 = f2bf(c - bf2f(h2)), l3 = f2bf(d - bf2f(h3));
    *(uint2*)&Tl[idx] = make_uint2((unsigned)l0 | ((unsigned)l1 << 16),
                                   (unsigned)l2 | ((unsigned)l3 << 16));
}

#define MFMA(A, B, C) __builtin_amdgcn_mfma_f32_16x16x32_bf16(A, B, C, 0, 0, 0)
#define FSWZ(lt) ((((lt) >> 1) ^ ((lt) >> 4)) & 7)

// ---------------------------------------------------------------------------
// Main: block = 128 tokens (2 rh rows), 4 waves; wave holds 32 tokens
// (2 col-tiles, bf16 hi/lo B-frags resident) -> each E-fragment ds_read is
// shared by 2 col-tiles (halves main-loop LDS traffic vs 16-tok waves).
// E streams through a 2x16 KB LDS double buffer via global_load_lds.
// bf16x3 split MFMA; score = ssqe - 2*dot. 4 acc chains (col x ks-parity).
// ---------------------------------------------------------------------------
__global__ __launch_bounds__(256, 3)
void vq_main_mfma(const float* __restrict__ x,
                  const float* __restrict__ Et,
                  const short* __restrict__ EhiSw,
                  const short* __restrict__ EloSw,
                  const float* __restrict__ ssqe,
                  float* __restrict__ out) {
    // region X [0,33024): union{ Thi 16K + Tlo 16K | Ebuf 2x16K | Q[32][257] }
    __shared__ __attribute__((aligned(16))) unsigned char smem[35584];
    short* Thi = (short*)smem;                 // [32*256]
    short* Tlo = (short*)(smem + 16384);
    float* Q   = (float*)smem;                 // [32][257]
    float* ssqe_sh = (float*)(smem + 33024);   // [512]
    int*   kstar   = (int*)(smem + 35072);     // [128]

    const int g   = blockIdx.x;                // 1024 blocks
    const int b   = g >> 5;
    const int rh2 = g & 31;                    // rh rows rh2*2, rh2*2+1
    const int tid = threadIdx.x;
    const int wv  = tid >> 6;
    const int ln  = tid & 63;
    const int r   = ln & 15;                   // A row (code) / C col (token)
    const int tq  = ln >> 4;                   // k-subgroup 0..3

    ssqe_sh[tid]       = ssqe[tid];
    ssqe_sh[tid + 256] = ssqe[tid + 256];

    short8 Bh0[8], Bl0[8], Bh1[8], Bl1[8];

    // ---- stage x in 4 passes of 32 tokens; wave p grabs its frags ----
    #pragma unroll
    for (int p = 0; p < 4; ++p) {
        const int rh_p = rh2 * 2 + (p >> 1);
        const float* xrow = x + (size_t)b * 1048576 + (size_t)rh_p * 256;
        #pragma unroll
        for (int i = 0; i < 2; ++i) {
            int j     = tid + i * 256;         // 0..511 : col4h(16) x c4(16) x s0(2)
            int col4h = j & 15;
            int rest  = j >> 4;
            int c4    = rest & 15;
            int s0    = rest >> 4;
            const float* pp = xrow + (c4 * 4) * 16384 + s0 * 128
                              + (p & 1) * 64 + col4h * 4;
            float4 v0 = *(const float4*)(pp);
            float4 v1 = *(const float4*)(pp + 16384);
            float4 v2 = *(const float4*)(pp + 32768);
            float4 v3 = *(const float4*)(pp + 49152);
            int ltA = col4h * 2, ltB = ltA + 1;
            int fA = FSWZ(ltA), fB = FSWZ(ltB);
            int d0 = s0 * 128 + c4 * 4, d1 = d0 + 64;
            stage4(Thi, Tlo, ltA, fA, d0, v0.x, v1.x, v2.x, v3.x);
            stage4(Thi, Tlo, ltA, fA, d1, v0.y, v1.y, v2.y, v3.y);
            stage4(Thi, Tlo, ltB, fB, d0, v0.z, v1.z, v2.z, v3.z);
            stage4(Thi, Tlo, ltB, fB, d1, v0.w, v1.w, v2.w, v3.w);
        }
        __syncthreads();
        if (wv == p) {                         // wave p owns tokens [32p,32p+32)
            int f0 = FSWZ(r), f1 = FSWZ(16 + r);
            #pragma unroll
            for (int ks = 0; ks < 8; ++ks) {
                int i0 = r * 256 + ((ks * 32 + tq * 8) ^ (f0 << 3));
                Bh0[ks] = *(const short8*)&Thi[i0];
                Bl0[ks] = *(const short8*)&Tlo[i0];
                int i1 = (16 + r) * 256 + ((ks * 32 + tq * 8) ^ (f1 << 3));
                Bh1[ks] = *(const short8*)&Thi[i1];
                Bl1[ks] = *(const short8*)&Tlo[i1];
            }
        }
        __syncthreads();
    }

    // ---- prologue: stage E tile 0 into buffer 0 ----
    {
        const char* hs = (const char*)EhiSw;
        const char* ls = (const char*)EloSw;
        char* d = (char*)smem;
        int o = wv * 1024 + ln * 16;
        gload_lds16(hs + o,        d + wv * 1024);
        gload_lds16(hs + o + 4096, d + wv * 1024 + 4096);
        gload_lds16(ls + o,        d + wv * 1024 + 8192);
        gload_lds16(ls + o + 4096, d + wv * 1024 + 12288);
    }
    __syncthreads();

    float best0 = __builtin_inff(), best1 = __builtin_inff();
    int   bi0 = 0, bi1 = 0;
    int   cur = 0;

    for (int ct = 0; ct < 32; ++ct) {
        if (ct < 31) {                          // prefetch next tile
            const char* hs = (const char*)EhiSw + (ct + 1) * 8192;
            const char* ls = (const char*)EloSw + (ct + 1) * 8192;
            char* d = (char*)smem + (cur ^ 1) * 16384;
            int o = wv * 1024 + ln * 16;
            gload_lds16(hs + o,        d + wv * 1024);
            gload_lds16(hs + o + 4096, d + wv * 1024 + 4096);
            gload_lds16(ls + o,        d + wv * 1024 + 8192);
            gload_lds16(ls + o + 4096, d + wv * 1024 + 12288);
        }
        const short* bh = (const short*)(smem + cur * 16384);
        const short* bl = bh + 4096;            // lo half at +8192 B
        f32x4 a0e = {0.f,0.f,0.f,0.f}, a0o = {0.f,0.f,0.f,0.f};
        f32x4 a1e = {0.f,0.f,0.f,0.f}, a1o = {0.f,0.f,0.f,0.f};
        #pragma unroll
        for (int ks = 0; ks < 8; ks += 2) {
            int off0 = r * 256 + 8 * ((ks * 4 + tq) ^ (r & 7));
            short8 ah0 = *(const short8*)&bh[off0];
            short8 al0 = *(const short8*)&bl[off0];
            int off1 = r * 256 + 8 * (((ks + 1) * 4 + tq) ^ (r & 7));
            short8 ah1 = *(const short8*)&bh[off1];
            short8 al1 = *(const short8*)&bl[off1];
            // each E-fragment feeds both col-tiles (read shared by 6 MFMAs)
            a0e = MFMA(ah0, Bh0[ks],     a0e);
            a1e = MFMA(ah0, Bh1[ks],     a1e);
            a0o = MFMA(ah1, Bh0[ks + 1], a0o);
            a1o = MFMA(ah1, Bh1[ks + 1], a1o);
            a0e = MFMA(ah0, Bl0[ks],     a0e);
            a1e = MFMA(ah0, Bl1[ks],     a1e);
            a0o = MFMA(ah1, Bl0[ks + 1], a0o);
            a1o = MFMA(ah1, Bl1[ks + 1], a1o);
            a0e = MFMA(al0, Bh0[ks],     a0e);
            a1e = MFMA(al0, Bh1[ks],     a1e);
            a0o = MFMA(al1, Bh0[ks + 1], a0o);
            a1o = MFMA(al1, Bh1[ks + 1], a1o);
        }
        float4 sq = *(const float4*)&ssqe_sh[ct * 16 + tq * 4];
        int kb = ct * 16 + tq * 4;
        #pragma unroll
        for (int jj = 0; jj < 4; ++jj) {
            float sqj = (jj == 0) ? sq.x : (jj == 1) ? sq.y : (jj == 2) ? sq.z : sq.w;
            float s0v = fmaf(-2.0f, a0e[jj] + a0o[jj], sqj);
            float s1v = fmaf(-2.0f, a1e[jj] + a1o[jj], sqj);
            if (s0v < best0) { best0 = s0v; bi0 = kb + jj; }
            if (s1v < best1) { best1 = s1v; bi1 = kb + jj; }
        }
        __syncthreads();                        // also drains prefetch vmcnt
        cur ^= 1;
    }

    // ---- argmin across tq groups (lanes r, r+16, r+32, r+48) ----
    #pragma unroll
    for (int m = 16; m <= 32; m <<= 1) {
        float ob = __shfl_xor(best0, m, 64);
        int   oi = __shfl_xor(bi0, m, 64);
        if (ob < best0 || (ob == best0 && oi < bi0)) { best0 = ob; bi0 = oi; }
        float pb = __shfl_xor(best1, m, 64);
        int   pi = __shfl_xor(bi1, m, 64);
        if (pb < best1 || (pb == best1 && pi < bi1)) { best1 = pb; bi1 = pi; }
    }
    if (tq == 0) {
        int t0 = wv * 32 + r, t1 = t0 + 16;
        kstar[t0] = bi0;
        kstar[t1] = bi1;
        // global token index = b*4096 + rh2*128 + t
        size_t ib = (size_t)OFF_IND + (size_t)b * 4096 + (size_t)rh2 * 128;
        out[ib + t0] = (float)bi0;
        out[ib + t1] = (float)bi1;
    }
    __syncthreads();                            // kstar ready; Ebuf dead -> Q

    // ---- epilogue: 4 passes of 32 tokens: gather -> Q -> out ----
    #pragma unroll
    for (int p = 0; p < 4; ++p) {
        if (p) __syncthreads();
        {
            int qt = tid & 31, part = tid >> 5;             // part 0..7
            const float* Erow = Et + (size_t)kstar[p * 32 + qt] * 256 + part * 32;
            float* qrow = Q + qt * 257 + part * 32;         // stride 257
            #pragma unroll
            for (int u = 0; u < 8; ++u) {
                float4 vv = *(const float4*)(Erow + u * 4);
                qrow[u * 4]     = vv.x;
                qrow[u * 4 + 1] = vv.y;
                qrow[u * 4 + 2] = vv.z;
                qrow[u * 4 + 3] = vv.w;
            }
        }
        __syncthreads();
        const int rh_p = rh2 * 2 + (p >> 1);
        float* ob2 = out + (size_t)b * 1048576 + (size_t)rh_p * 256 + (p & 1) * 64;
        #pragma unroll
        for (int i = 0; i < 8; ++i) {
            int j     = tid + i * 256;          // 0..2047: col4h(16) x (c,s0)(128)
            int col4h = j & 15;
            int rest  = j >> 4;
            int c  = rest >> 1;
            int s0 = rest & 1;
            int ltA = col4h * 2, ltB = ltA + 1;
            int d0 = s0 * 128 + c, d1 = d0 + 64;
            float4 v;
            v.x = Q[ltA * 257 + d0];
            v.y = Q[ltA * 257 + d1];
            v.z = Q[ltB * 257 + d0];
            v.w = Q[ltB * 257 + d1];
            *(float4*)(ob2 + c * 16384 + s0 * 128 + col4h * 4) = v;
        }
    }
}

// ---------------------------------------------------------------------------
// Fallback (ws too small): proven round-3 f32 path
// ---------------------------------------------------------------------------
__global__ void vq_prep(const float* __restrict__ E,
                        float* __restrict__ ssqe,
                        float* __restrict__ out) {
    int k = blockIdx.x * 256 + threadIdx.x;
    float acc = 0.0f;
    #pragma unroll 8
    for (int d = 0; d < 256; ++d) {
        float e = E[d * 512 + k];
        acc = fmaf(e, e, acc);
    }
    ssqe[k] = acc;
    if (k == 0) { out[OFF_DIFF] = 0.0f; out[OFF_PERP] = 0.0f; }
}

__global__ __launch_bounds__(256, 2)
void vq_main_f32(const float* __restrict__ x,
                 const float* __restrict__ E,
                 const float* __restrict__ ssqe,
                 float* __restrict__ out) {
    __shared__ float A[256 * 64];
    __shared__ float redD[4][64];
    __shared__ int   redI[4][64];
    __shared__ int   kstar_sh[64];

    const int g = blockIdx.x, b = g >> 6, rh = g & 63, tid = threadIdx.x;
    const float* xbase = x + (size_t)b * 1048576 + rh * 256;

    #pragma unroll
    for (int i = 0; i < 16; ++i) {
        int j = tid + i * 256;
        int row = j >> 5, col4 = j & 31;
        int c = row >> 1, s0 = row & 1;
        const float4 v = *(const float4*)(xbase + c * 16384 + s0 * 128 + col4 * 4);
        int tokk = col4 * 2;
        int d0 = s0 * 128 + c, d1 = d0 + 64;
        *(float2*)&A[d0 * 64 + tokk] = make_float2(v.x, v.z);
        *(float2*)&A[d1 * 64 + tokk] = make_float2(v.y, v.w);
    }
    __syncthreads();

    const int wave = tid >> 6, lane = tid & 63;
    float ssq = 0.0f;
    #pragma unroll 8
    for (int d = 0; d < 256; ++d) { float a = A[d * 64 + lane]; ssq = fmaf(a, a, ssq); }

    const int K0 = __builtin_amdgcn_readfirstlane(wave * 128);
    float best = __builtin_inff();
    int besti = 0;
    for (int chunk = 0; chunk < 8; ++chunk) {
        const int k0 = K0 + chunk * 16;
        const float* __restrict__ Ep = E + k0;
        float acc[16];
        #pragma unroll
        for (int j = 0; j < 16; ++j) acc[j] = 0.0f;
        #pragma unroll 4
        for (int d = 0; d < 256; ++d) {
            float a = A[d * 64 + lane];
            #pragma unroll
            for (int j = 0; j < 16; ++j) acc[j] = fmaf(a, Ep[d * 512 + j], acc[j]);
        }
        #pragma unroll
        for (int j = 0; j < 16; ++j) {
            float dist = (ssq - 2.0f * acc[j]) + ssqe[k0 + j];
            if (dist < best) { best = dist; besti = k0 + j; }
        }
    }
    redD[wave][lane] = best; redI[wave][lane] = besti;
    __syncthreads();
    if (tid < 64) {
        float bd = redD[0][tid]; int bi = redI[0][tid];
        #pragma unroll
        for (int w = 1; w < 4; ++w) {
            float dd = redD[w][tid];
            if (dd < bd) { bd = dd; bi = redI[w][tid]; }
        }
        kstar_sh[tid] = bi;
        out[OFF_IND + g * 64 + tid] = (float)bi;
    }
    __syncthreads();
    float* obase = out + (size_t)b * 1048576 + rh * 256;
    #pragma unroll
    for (int i = 0; i < 16; ++i) {
        int j = tid + i * 256;
        int row = j >> 5, col4 = j & 31;
        int c = row >> 1, s0 = row & 1;
        int tokA = col4 * 2, tokB = tokA + 1;
        int kA = kstar_sh[tokA], kB = kstar_sh[tokB];
        int d0 = s0 * 128 + c, d1 = d0 + 64;
        float4 v;
        v.x = E[d0 * 512 + kA]; v.y = E[d1 * 512 + kA];
        v.z = E[d0 * 512 + kB]; v.w = E[d1 * 512 + kB];
        *(float4*)(obase + c * 16384 + s0 * 128 + col4 * 4) = v;
    }
}

extern "C" void kernel_launch(void* const* d_in, const int* in_sizes, int n_in,
                              void* d_out, int out_size, void* d_ws, size_t ws_size,
                              hipStream_t stream) {
    const float* x = (const float*)d_in[0];
    const float* E = (const float*)d_in[1];
    float* out = (float*)d_out;

    // ws: ssqe f32[512] @0 | Et f32[512*256] @4096 | EhiSw @528384 | EloSw @790528
    float* ssqe  = (float*)d_ws;
    float* Et    = (float*)((char*)d_ws + 4096);
    short* EhiSw = (short*)((char*)d_ws + 528384);
    short* EloSw = (short*)((char*)d_ws + 790528);
    const size_t need = 1052672;

    if (ws_size >= need) {
        hipLaunchKernelGGL(vq_split, dim3(512), dim3(64), 0, stream,
                           E, Et, EhiSw, EloSw, ssqe, out);
        hipLaunchKernelGGL(vq_main_mfma, dim3(1024), dim3(256), 0, stream,
                           x, Et, EhiSw, EloSw, ssqe, out);
    } else {
        hipLaunchKernelGGL(vq_prep, dim3(2), dim3(256), 0, stream, E, ssqe, out);
        hipLaunchKernelGGL(vq_main_f32, dim3(2048), dim3(256), 0, stream,
                           x, E, ssqe, out);
    }
}